// Round 2
// baseline (11181.281 us; speedup 1.0000x reference)
//
#include <hip/hip_runtime.h>
#include <hip/hip_bf16.h>
#include <hip/hip_cooperative_groups.h>
#include <math.h>

namespace cg = cooperative_groups;

// Problem constants
#define B 32
#define SENC 64
#define SDEC 32
#define HDIM 512
#define EDIM 512
#define VDIM 32000
#define G4 2048              // 4*H
#define BH (B*HDIM)          // 16384

// LDS strides: 2*stride % 32 == 8 -> adjacent lane pairs land 8 banks apart,
// only 2-way aliasing (free per m136).
#define WS 516               // enc weight/act row stride (512 cols used)
#define AS 1028              // dec act row stride (up to 1024 cols used)
#define PBS 17               // pbuf row stride

__device__ __forceinline__ float sigm(float x) { return 1.f / (1.f + expf(-x)); }

__device__ __forceinline__ float allreduce64(float v)
{
    #pragma unroll
    for (int m = 1; m < 64; m <<= 1) v += __shfl_xor(v, m);
    return v;
}

// ---------------------------------------------------------------------------
// embed: gather emb rows for xs tokens
// ---------------------------------------------------------------------------
__global__ __launch_bounds__(128) void embed_kernel(const int* __restrict__ toks,
                                                    const float* __restrict__ emb,
                                                    float* __restrict__ out)
{
    int t = blockIdx.x;
    int id = toks[t];
    const float4* src = (const float4*)(emb + (size_t)id * EDIM);
    float4* dst = (float4*)(out + (size_t)t * EDIM);
    dst[threadIdx.x] = src[threadIdx.x];
}

// ---------------------------------------------------------------------------
// Generic NT SGEMM: C[m,n] = sum_k A[m*K+k]*B[n*K+k] (+bias0[n]+bias1[n])
// block tile 128x64, 256 threads, 8x4 microtile.
// ---------------------------------------------------------------------------
__global__ __launch_bounds__(256) void gemm_nt(const float* __restrict__ A,
                                               const float* __restrict__ Bm,
                                               float* __restrict__ C,
                                               const float* __restrict__ bias0,
                                               const float* __restrict__ bias1,
                                               int M, int N, int K)
{
    __shared__ float As[16][128];
    __shared__ float Bs[16][64];
    int tid = threadIdx.x;
    int tx = tid & 15, ty = tid >> 4;
    int m0 = blockIdx.y * 128, n0 = blockIdx.x * 64;

    float acc[8][4];
    #pragma unroll
    for (int i = 0; i < 8; i++)
        #pragma unroll
        for (int j = 0; j < 4; j++) acc[i][j] = 0.f;

    int la_m = tid >> 1, la_k = (tid & 1) * 8;
    int lb_n = tid & 63, lb_k = (tid >> 6) * 4;
    const float* Aptr = A + (size_t)(m0 + la_m) * K + la_k;
    const float* Bptr = Bm + (size_t)(n0 + lb_n) * K + lb_k;

    for (int k0 = 0; k0 < K; k0 += 16) {
        float4 a1 = *(const float4*)(Aptr + k0);
        float4 a2 = *(const float4*)(Aptr + k0 + 4);
        float4 bv = *(const float4*)(Bptr + k0);
        As[la_k + 0][la_m] = a1.x; As[la_k + 1][la_m] = a1.y;
        As[la_k + 2][la_m] = a1.z; As[la_k + 3][la_m] = a1.w;
        As[la_k + 4][la_m] = a2.x; As[la_k + 5][la_m] = a2.y;
        As[la_k + 6][la_m] = a2.z; As[la_k + 7][la_m] = a2.w;
        Bs[lb_k + 0][lb_n] = bv.x; Bs[lb_k + 1][lb_n] = bv.y;
        Bs[lb_k + 2][lb_n] = bv.z; Bs[lb_k + 3][lb_n] = bv.w;
        __syncthreads();
        #pragma unroll
        for (int kk = 0; kk < 16; kk++) {
            float4 av1 = *(const float4*)&As[kk][ty * 8];
            float4 av2 = *(const float4*)&As[kk][ty * 8 + 4];
            float4 bvv = *(const float4*)&Bs[kk][tx * 4];
            float am[8] = {av1.x, av1.y, av1.z, av1.w, av2.x, av2.y, av2.z, av2.w};
            float bn[4] = {bvv.x, bvv.y, bvv.z, bvv.w};
            #pragma unroll
            for (int i = 0; i < 8; i++)
                #pragma unroll
                for (int j = 0; j < 4; j++)
                    acc[i][j] += am[i] * bn[j];
        }
        __syncthreads();
    }

    float bb[4] = {0.f, 0.f, 0.f, 0.f};
    int nc = n0 + tx * 4;
    if (bias0) {
        #pragma unroll
        for (int j = 0; j < 4; j++) bb[j] += bias0[nc + j];
    }
    if (bias1) {
        #pragma unroll
        for (int j = 0; j < 4; j++) bb[j] += bias1[nc + j];
    }
    #pragma unroll
    for (int i = 0; i < 8; i++) {
        int row = m0 + ty * 8 + i;
        float4 o = make_float4(acc[i][0] + bb[0], acc[i][1] + bb[1],
                               acc[i][2] + bb[2], acc[i][3] + bb[3]);
        *(float4*)(C + (size_t)row * N + nc) = o;
    }
}

// ---------------------------------------------------------------------------
// Persistent cooperative encoder layer: 64 timesteps with grid sync.
// Grid 256 x 256. Block = 4 jh x 4 gates (16 rows) x 16 batch.
// Whh slice cached in LDS once; c-state in registers; h ping-pong in global.
// ---------------------------------------------------------------------------
__global__ __launch_bounds__(256, 1) void enc_layer(
    const float* __restrict__ xg,     // [B*SENC, 2048] = x@Wih^T + bih + bhh
    const float* __restrict__ Whh,    // [2048, 512]
    float* __restrict__ seq_out,      // [B*SENC, 512]
    float* __restrict__ hping,        // [2][BH]
    float* __restrict__ hT,           // [BH]
    float* __restrict__ cT)           // [BH]
{
    cg::grid_group grid = cg::this_grid();
    __shared__ float wsh[16 * WS];
    __shared__ float hsh[16 * WS];
    __shared__ float pbuf[4 * 16 * PBS];

    int tid = threadIdx.x;
    int cid = blockIdx.x >> 1, bg = blockIdx.x & 1;
    int jh0 = cid * 4, b0 = bg * 16;

    // preload weight slice: rows r -> gate g=r>>2, jl=r&3
    for (int idx = tid; idx < 16 * 128; idx += 256) {
        int r = idx >> 7, kq = idx & 127;
        int grow = (r >> 2) * 512 + jh0 + (r & 3);
        *(float4*)(wsh + r * WS + kq * 4) =
            *(const float4*)(Whh + (size_t)grow * 512 + kq * 4);
    }

    int kseg = tid >> 6, rp = (tid >> 3) & 7, bp = tid & 7;
    const float* w0 = wsh + (2 * rp) * WS + kseg * 128;
    const float* w1 = wsh + (2 * rp + 1) * WS + kseg * 128;
    const float* h0 = hsh + (2 * bp) * WS + kseg * 128;
    const float* h1 = hsh + (2 * bp + 1) * WS + kseg * 128;

    int pjl = tid >> 4, pb = tid & 15;      // pointwise thread (tid<64)
    float c_reg = 0.f;

    for (int t = 0; t < SENC; t++) {
        const float* hin = hping + (t & 1) * BH;
        float* hout = hping + ((t & 1) ^ 1) * BH;
        // stage h(t)
        if (t == 0) {
            float4 z = make_float4(0.f, 0.f, 0.f, 0.f);
            for (int idx = tid; idx < 16 * 128; idx += 256)
                *(float4*)(hsh + (idx >> 7) * WS + (idx & 127) * 4) = z;
        } else {
            for (int idx = tid; idx < 16 * 128; idx += 256) {
                int bb = idx >> 7, kq = idx & 127;
                *(float4*)(hsh + bb * WS + kq * 4) =
                    *(const float4*)(hin + (size_t)(b0 + bb) * 512 + kq * 4);
            }
        }
        __syncthreads();

        float s00 = 0.f, s01 = 0.f, s10 = 0.f, s11 = 0.f;
        #pragma unroll 4
        for (int k = 0; k < 128; k += 4) {
            float4 wa = *(const float4*)(w0 + k);
            float4 wb = *(const float4*)(w1 + k);
            float4 xa = *(const float4*)(h0 + k);
            float4 xb = *(const float4*)(h1 + k);
            s00 += wa.x * xa.x + wa.y * xa.y + wa.z * xa.z + wa.w * xa.w;
            s01 += wa.x * xb.x + wa.y * xb.y + wa.z * xb.z + wa.w * xb.w;
            s10 += wb.x * xa.x + wb.y * xa.y + wb.z * xa.z + wb.w * xa.w;
            s11 += wb.x * xb.x + wb.y * xb.y + wb.z * xb.z + wb.w * xb.w;
        }
        pbuf[(kseg * 16 + 2 * rp) * PBS + 2 * bp]         = s00;
        pbuf[(kseg * 16 + 2 * rp) * PBS + 2 * bp + 1]     = s01;
        pbuf[(kseg * 16 + 2 * rp + 1) * PBS + 2 * bp]     = s10;
        pbuf[(kseg * 16 + 2 * rp + 1) * PBS + 2 * bp + 1] = s11;
        __syncthreads();

        if (tid < 64) {
            int bglob = b0 + pb, jh = jh0 + pjl;
            size_t xrow = (size_t)(bglob * SENC + t) * G4;
            float gv[4];
            #pragma unroll
            for (int g = 0; g < 4; g++) {
                int r = g * 4 + pjl;
                gv[g] = pbuf[(0 * 16 + r) * PBS + pb] + pbuf[(1 * 16 + r) * PBS + pb]
                      + pbuf[(2 * 16 + r) * PBS + pb] + pbuf[(3 * 16 + r) * PBS + pb]
                      + xg[xrow + g * 512 + jh];
            }
            float ci = sigm(gv[0]), cf = sigm(gv[1]);
            float cg_ = tanhf(gv[2]), co = sigm(gv[3]);
            c_reg = cf * c_reg + ci * cg_;
            float hn = co * tanhf(c_reg);
            hout[bglob * 512 + jh] = hn;
            seq_out[(size_t)(bglob * SENC + t) * 512 + jh] = hn;
            if (t == SENC - 1) {
                hT[bglob * 512 + jh] = hn;
                cT[bglob * 512 + jh] = c_reg;
            }
        }
        grid.sync();
    }
}

// ---------------------------------------------------------------------------
// Persistent cooperative decoder: 32 steps of attention + 2 LSTM cells.
// Grid 256 x 256, 5 grid syncs per step.
// ---------------------------------------------------------------------------
__global__ __launch_bounds__(256, 1) void dec_seq(
    const int* __restrict__ xs, const int* __restrict__ ys,
    const float* __restrict__ emb,
    const float* __restrict__ attnW, const float* __restrict__ combW,
    const float* __restrict__ Wih0, const float* __restrict__ Whh0,
    const float* __restrict__ bih0, const float* __restrict__ bhh0,
    const float* __restrict__ Wih1, const float* __restrict__ Whh1,
    const float* __restrict__ bih1, const float* __restrict__ bhh1,
    const float* __restrict__ enc_out,
    const float* __restrict__ c0init, const float* __restrict__ c1init,
    float* __restrict__ hb0,          // [2][BH], slot0 = enc hT layer0
    float* __restrict__ hb1,          // [2][BH], slot0 = enc hT layer1
    float* __restrict__ hid_g,        // [BH]
    float* __restrict__ xc_g,         // [B*1024]
    float* __restrict__ inp_g,        // [BH]
    float* __restrict__ h2buf)        // [B*SDEC, 512]
{
    cg::grid_group grid = cg::this_grid();
    __shared__ float ash[16 * AS];
    __shared__ float pbuf[4 * 16 * PBS];
    __shared__ float misc[704];       // hidl 512 | pw 64 | aw 64

    int tid = threadIdx.x;
    int cid = blockIdx.x;
    int kseg = tid >> 6, rp = (tid >> 3) & 7, bp = tid & 7;

    // cell partition (all 256 blocks)
    int jh0 = (cid >> 1) * 4, cb0 = (cid & 1) * 16;
    int pjl = tid >> 4, pb = tid & 15;
    float c0 = 0.f, c1 = 0.f;
    float bs0[4], bs1[4];
    int grow_c[4];
    if (tid < 64) {
        int bglob = cb0 + pb, jh = jh0 + pjl;
        c0 = c0init[bglob * 512 + jh];
        c1 = c1init[bglob * 512 + jh];
        #pragma unroll
        for (int g = 0; g < 4; g++) {
            int grow = g * 512 + jh;
            grow_c[g] = grow;
            bs0[g] = bih0[grow] + bhh0[grow];
            bs1[g] = bih1[grow] + bhh1[grow];
        }
    }
    // cell weight rows for this thread
    int crow0 = ((2 * rp) >> 2) * 512 + jh0 + ((2 * rp) & 3);
    int crow1 = ((2 * rp + 1) >> 2) * 512 + jh0 + ((2 * rp + 1) & 3);

    int p0 = 0, p1 = 0;
    for (int t = 0; t < SDEC; t++) {
        // ---- phase 1: hid = h2 @ attnW^T  (blocks 0..63) ----
        if (cid < 64) {
            int e0 = (cid >> 1) * 16, b0 = (cid & 1) * 16;
            const float* h2 = hb1 + p1 * BH;
            for (int idx = tid; idx < 16 * 128; idx += 256) {
                int bb = idx >> 7, kq = idx & 127;
                *(float4*)(ash + bb * AS + kq * 4) =
                    *(const float4*)(h2 + (size_t)(b0 + bb) * 512 + kq * 4);
            }
            __syncthreads();
            const float* w0 = attnW + (size_t)(e0 + 2 * rp) * 512 + kseg * 128;
            const float* w1 = attnW + (size_t)(e0 + 2 * rp + 1) * 512 + kseg * 128;
            const float* a0 = ash + (2 * bp) * AS + kseg * 128;
            const float* a1 = ash + (2 * bp + 1) * AS + kseg * 128;
            float s00 = 0.f, s01 = 0.f, s10 = 0.f, s11 = 0.f;
            #pragma unroll 4
            for (int k = 0; k < 128; k += 4) {
                float4 wa = *(const float4*)(w0 + k);
                float4 wb = *(const float4*)(w1 + k);
                float4 xa = *(const float4*)(a0 + k);
                float4 xb = *(const float4*)(a1 + k);
                s00 += wa.x * xa.x + wa.y * xa.y + wa.z * xa.z + wa.w * xa.w;
                s01 += wa.x * xb.x + wa.y * xb.y + wa.z * xb.z + wa.w * xb.w;
                s10 += wb.x * xa.x + wb.y * xa.y + wb.z * xa.z + wb.w * xa.w;
                s11 += wb.x * xb.x + wb.y * xb.y + wb.z * xb.z + wb.w * xb.w;
            }
            pbuf[(kseg * 16 + 2 * rp) * PBS + 2 * bp]         = s00;
            pbuf[(kseg * 16 + 2 * rp) * PBS + 2 * bp + 1]     = s01;
            pbuf[(kseg * 16 + 2 * rp + 1) * PBS + 2 * bp]     = s10;
            pbuf[(kseg * 16 + 2 * rp + 1) * PBS + 2 * bp + 1] = s11;
            __syncthreads();
            int e_l = tid >> 4, b_l = tid & 15;
            float v = pbuf[(0 * 16 + e_l) * PBS + b_l] + pbuf[(1 * 16 + e_l) * PBS + b_l]
                    + pbuf[(2 * 16 + e_l) * PBS + b_l] + pbuf[(3 * 16 + e_l) * PBS + b_l];
            hid_g[(b0 + b_l) * 512 + e0 + e_l] = v;
        }
        grid.sync();

        // ---- phase 2: pw, softmax, ctx, xe gather (blocks 0..31, one per b) ----
        if (cid < 32) {
            int b = cid;
            float* hidl = misc;
            float* pwsh = misc + 512;
            float* awsh = misc + 576;
            for (int i = tid; i < 512; i += 256) hidl[i] = hid_g[b * 512 + i];
            __syncthreads();
            int wave = tid >> 6, lane = tid & 63;
            #pragma unroll
            for (int i = 0; i < 16; i++) {
                int s = wave * 16 + i;
                const float* er = enc_out + (size_t)(b * SENC + s) * 512 + lane * 8;
                float4 q1 = *(const float4*)er;
                float4 q2 = *(const float4*)(er + 4);
                float4 hv1 = *(const float4*)(hidl + lane * 8);
                float4 hv2 = *(const float4*)(hidl + lane * 8 + 4);
                float pp = q1.x * hv1.x + q1.y * hv1.y + q1.z * hv1.z + q1.w * hv1.w
                         + q2.x * hv2.x + q2.y * hv2.y + q2.z * hv2.z + q2.w * hv2.w;
                pp = allreduce64(pp);
                if (lane == 0)
                    pwsh[s] = pp - ((xs[b * SENC + s] > 0) ? 0.f : 1e20f);
            }
            __syncthreads();
            if (tid < 64) {
                float v = pwsh[tid];
                float m = v;
                #pragma unroll
                for (int o = 1; o < 64; o <<= 1) m = fmaxf(m, __shfl_xor(m, o));
                float ex = expf(v - m);
                float sm = ex;
                #pragma unroll
                for (int o = 1; o < 64; o <<= 1) sm += __shfl_xor(sm, o);
                awsh[tid] = ex / sm;
            }
            __syncthreads();
            int yt = ys[b * SDEC + t];
            for (int e = tid; e < 512; e += 256) {
                float acc = 0.f;
                for (int s = 0; s < 64; s++)
                    acc += awsh[s] * enc_out[(size_t)(b * SENC + s) * 512 + e];
                xc_g[b * 1024 + 512 + e] = acc;
                xc_g[b * 1024 + e] = emb[(size_t)yt * EDIM + e];
            }
        }
        grid.sync();

        // ---- phase 3: inp = tanh(xc @ combW^T)  (blocks 0..63) ----
        if (cid < 64) {
            int e0 = (cid >> 1) * 16, b0 = (cid & 1) * 16;
            for (int idx = tid; idx < 16 * 256; idx += 256) {
                int bb = idx >> 8, kq = idx & 255;
                *(float4*)(ash + bb * AS + kq * 4) =
                    *(const float4*)(xc_g + (size_t)(b0 + bb) * 1024 + kq * 4);
            }
            __syncthreads();
            const float* w0 = combW + (size_t)(e0 + 2 * rp) * 1024 + kseg * 256;
            const float* w1 = combW + (size_t)(e0 + 2 * rp + 1) * 1024 + kseg * 256;
            const float* a0 = ash + (2 * bp) * AS + kseg * 256;
            const float* a1 = ash + (2 * bp + 1) * AS + kseg * 256;
            float s00 = 0.f, s01 = 0.f, s10 = 0.f, s11 = 0.f;
            #pragma unroll 4
            for (int k = 0; k < 256; k += 4) {
                float4 wa = *(const float4*)(w0 + k);
                float4 wb = *(const float4*)(w1 + k);
                float4 xa = *(const float4*)(a0 + k);
                float4 xb = *(const float4*)(a1 + k);
                s00 += wa.x * xa.x + wa.y * xa.y + wa.z * xa.z + wa.w * xa.w;
                s01 += wa.x * xb.x + wa.y * xb.y + wa.z * xb.z + wa.w * xb.w;
                s10 += wb.x * xa.x + wb.y * xa.y + wb.z * xa.z + wb.w * xa.w;
                s11 += wb.x * xb.x + wb.y * xb.y + wb.z * xb.z + wb.w * xb.w;
            }
            pbuf[(kseg * 16 + 2 * rp) * PBS + 2 * bp]         = s00;
            pbuf[(kseg * 16 + 2 * rp) * PBS + 2 * bp + 1]     = s01;
            pbuf[(kseg * 16 + 2 * rp + 1) * PBS + 2 * bp]     = s10;
            pbuf[(kseg * 16 + 2 * rp + 1) * PBS + 2 * bp + 1] = s11;
            __syncthreads();
            int e_l = tid >> 4, b_l = tid & 15;
            float v = pbuf[(0 * 16 + e_l) * PBS + b_l] + pbuf[(1 * 16 + e_l) * PBS + b_l]
                    + pbuf[(2 * 16 + e_l) * PBS + b_l] + pbuf[(3 * 16 + e_l) * PBS + b_l];
            inp_g[(b0 + b_l) * 512 + e0 + e_l] = tanhf(v);
        }
        grid.sync();

        // ---- phases 4/5: LSTM cells (all 256 blocks) ----
        #pragma unroll
        for (int layer = 0; layer < 2; layer++) {
            const float* invec = (layer == 0) ? inp_g : (hb0 + (p0 ^ 1) * BH);
            const float* hprev = (layer == 0) ? (hb0 + p0 * BH) : (hb1 + p1 * BH);
            float* hnew = (layer == 0) ? (hb0 + (p0 ^ 1) * BH) : (hb1 + (p1 ^ 1) * BH);
            const float* Wih = (layer == 0) ? Wih0 : Wih1;
            const float* Whh = (layer == 0) ? Whh0 : Whh1;

            // stage [invec || hprev] for 16 batch rows
            for (int idx = tid; idx < 16 * 256; idx += 256) {
                int bb = idx >> 8, kq = idx & 255;
                const float* src = (kq < 128)
                    ? (invec + (size_t)(cb0 + bb) * 512 + kq * 4)
                    : (hprev + (size_t)(cb0 + bb) * 512 + (kq - 128) * 4);
                *(float4*)(ash + bb * AS + kq * 4) = *(const float4*)src;
            }
            __syncthreads();
            const float* wbase = (kseg < 2) ? Wih : Whh;
            int kadj = (kseg < 2) ? kseg * 256 : (kseg - 2) * 256;
            const float* w0 = wbase + (size_t)crow0 * 512 + kadj;
            const float* w1 = wbase + (size_t)crow1 * 512 + kadj;
            const float* a0 = ash + (2 * bp) * AS + kseg * 256;
            const float* a1 = ash + (2 * bp + 1) * AS + kseg * 256;
            float s00 = 0.f, s01 = 0.f, s10 = 0.f, s11 = 0.f;
            #pragma unroll 4
            for (int k = 0; k < 256; k += 4) {
                float4 wa = *(const float4*)(w0 + k);
                float4 wb = *(const float4*)(w1 + k);
                float4 xa = *(const float4*)(a0 + k);
                float4 xb = *(const float4*)(a1 + k);
                s00 += wa.x * xa.x + wa.y * xa.y + wa.z * xa.z + wa.w * xa.w;
                s01 += wa.x * xb.x + wa.y * xb.y + wa.z * xb.z + wa.w * xb.w;
                s10 += wb.x * xa.x + wb.y * xa.y + wb.z * xa.z + wb.w * xa.w;
                s11 += wb.x * xb.x + wb.y * xb.y + wb.z * xb.z + wb.w * xb.w;
            }
            pbuf[(kseg * 16 + 2 * rp) * PBS + 2 * bp]         = s00;
            pbuf[(kseg * 16 + 2 * rp) * PBS + 2 * bp + 1]     = s01;
            pbuf[(kseg * 16 + 2 * rp + 1) * PBS + 2 * bp]     = s10;
            pbuf[(kseg * 16 + 2 * rp + 1) * PBS + 2 * bp + 1] = s11;
            __syncthreads();
            if (tid < 64) {
                float gv[4];
                #pragma unroll
                for (int g = 0; g < 4; g++) {
                    int r = g * 4 + pjl;
                    gv[g] = pbuf[(0 * 16 + r) * PBS + pb] + pbuf[(1 * 16 + r) * PBS + pb]
                          + pbuf[(2 * 16 + r) * PBS + pb] + pbuf[(3 * 16 + r) * PBS + pb]
                          + ((layer == 0) ? bs0[g] : bs1[g]);
                }
                float ci = sigm(gv[0]), cf = sigm(gv[1]);
                float cg_ = tanhf(gv[2]), co = sigm(gv[3]);
                float& cref = (layer == 0) ? c0 : c1;
                cref = cf * cref + ci * cg_;
                float hn = co * tanhf(cref);
                int bglob = cb0 + pb, jh = jh0 + pjl;
                hnew[bglob * 512 + jh] = hn;
                if (layer == 1)
                    h2buf[(size_t)(bglob * SDEC + t) * 512 + jh] = hn;
            }
            grid.sync();
        }
        p0 ^= 1;
        p1 ^= 1;
    }
}

// ---------------------------------------------------------------------------
// argmax over scores[m, 1:], lowest index on ties
// ---------------------------------------------------------------------------
__global__ __launch_bounds__(256) void argmax_kernel(const float* __restrict__ scores,
                                                     float* __restrict__ preds)
{
    __shared__ float sv[256];
    __shared__ int si[256];
    int m = blockIdx.x;
    const float* row = scores + (size_t)m * VDIM;
    float best = -3.4e38f;
    int bi = 0x7fffffff;
    for (int v = 1 + (int)threadIdx.x; v < VDIM; v += 256) {
        float val = row[v];
        if (val > best) { best = val; bi = v; }
    }
    sv[threadIdx.x] = best;
    si[threadIdx.x] = bi;
    __syncthreads();
    for (int s = 128; s > 0; s >>= 1) {
        if ((int)threadIdx.x < s) {
            float ov = sv[threadIdx.x + s];
            int oi = si[threadIdx.x + s];
            if (ov > sv[threadIdx.x] ||
                (ov == sv[threadIdx.x] && oi < si[threadIdx.x])) {
                sv[threadIdx.x] = ov;
                si[threadIdx.x] = oi;
            }
        }
        __syncthreads();
    }
    if (threadIdx.x == 0) preds[m] = (float)si[0];
}

// ---------------------------------------------------------------------------
extern "C" void kernel_launch(void* const* d_in, const int* in_sizes, int n_in,
                              void* d_out, int out_size, void* d_ws, size_t ws_size,
                              hipStream_t stream)
{
    const int* xs = (const int*)d_in[0];
    const int* ys = (const int*)d_in[1];
    const float* emb = (const float*)d_in[2];
    const float* W[16];
    for (int i = 0; i < 16; i++) W[i] = (const float*)d_in[3 + i];
    const float* attnW = (const float*)d_in[19];
    const float* combW = (const float*)d_in[20];
    float* out = (float*)d_out;
    float* ws = (float*)d_ws;

    // workspace layout (floats)
    float* xemb  = ws;                    // 1,048,576 (also h2buf overlay later)
    float* xg    = xemb + 1048576;        // 4,194,304
    float* l0out = xg + 4194304;          // 1,048,576
    float* l1out = l0out + 1048576;       // 1,048,576 (enc_out)
    float* ench  = l1out + 1048576;       // 2*BH encoder h ping-pong
    float* hb0   = ench + 2 * BH;         // 2*BH
    float* hb1   = hb0 + 2 * BH;          // 2*BH
    float* c0buf = hb1 + 2 * BH;          // BH
    float* c1buf = c0buf + BH;            // BH
    // decoder overlays (xg dead after encoder)
    float* hid_g = xg;                    // BH
    float* xc_g  = xg + BH;               // 32*1024
    float* inp_g = xc_g + B * 1024;       // BH
    float* h2buf = xemb;                  // B*SDEC*512 = 524,288 (xemb dead)

    // ---- Encoder ----
    embed_kernel<<<B * SENC, 128, 0, stream>>>(xs, emb, xemb);

    // layer 0
    gemm_nt<<<dim3(G4 / 64, (B * SENC) / 128), 256, 0, stream>>>(
        xemb, W[0], xg, W[2], W[3], B * SENC, G4, 512);
    {
        const float* a_xg = xg; const float* a_whh = W[1];
        float* a_seq = l0out; float* a_hp = ench;
        float* a_hT = hb0; float* a_cT = c0buf;
        void* args[] = {(void*)&a_xg, (void*)&a_whh, (void*)&a_seq,
                        (void*)&a_hp, (void*)&a_hT, (void*)&a_cT};
        hipLaunchCooperativeKernel((void*)enc_layer, dim3(256), dim3(256),
                                   args, 0, stream);
    }
    // layer 1
    gemm_nt<<<dim3(G4 / 64, (B * SENC) / 128), 256, 0, stream>>>(
        l0out, W[4], xg, W[6], W[7], B * SENC, G4, 512);
    {
        const float* a_xg = xg; const float* a_whh = W[5];
        float* a_seq = l1out; float* a_hp = ench;
        float* a_hT = hb1; float* a_cT = c1buf;
        void* args[] = {(void*)&a_xg, (void*)&a_whh, (void*)&a_seq,
                        (void*)&a_hp, (void*)&a_hT, (void*)&a_cT};
        hipLaunchCooperativeKernel((void*)enc_layer, dim3(256), dim3(256),
                                   args, 0, stream);
    }

    // ---- Decoder (persistent) ----
    {
        const int* a_xs = xs; const int* a_ys = ys;
        const float* a_emb = emb;
        const float* a_attn = attnW; const float* a_comb = combW;
        const float* a_wih0 = W[8];  const float* a_whh0 = W[9];
        const float* a_bih0 = W[10]; const float* a_bhh0 = W[11];
        const float* a_wih1 = W[12]; const float* a_whh1 = W[13];
        const float* a_bih1 = W[14]; const float* a_bhh1 = W[15];
        const float* a_enc = l1out;
        const float* a_c0 = c0buf; const float* a_c1 = c1buf;
        float* a_hb0 = hb0; float* a_hb1 = hb1;
        float* a_hid = hid_g; float* a_xc = xc_g; float* a_inp = inp_g;
        float* a_h2 = h2buf;
        void* args[] = {(void*)&a_xs, (void*)&a_ys, (void*)&a_emb,
                        (void*)&a_attn, (void*)&a_comb,
                        (void*)&a_wih0, (void*)&a_whh0, (void*)&a_bih0, (void*)&a_bhh0,
                        (void*)&a_wih1, (void*)&a_whh1, (void*)&a_bih1, (void*)&a_bhh1,
                        (void*)&a_enc, (void*)&a_c0, (void*)&a_c1,
                        (void*)&a_hb0, (void*)&a_hb1,
                        (void*)&a_hid, (void*)&a_xc, (void*)&a_inp, (void*)&a_h2};
        hipLaunchCooperativeKernel((void*)dec_seq, dim3(256), dim3(256),
                                   args, 0, stream);
    }

    // ---- Output projection + argmax ----
    gemm_nt<<<dim3(VDIM / 64, (B * SDEC) / 128), 256, 0, stream>>>(
        h2buf, emb, out + B * SDEC, nullptr, nullptr, B * SDEC, VDIM, 512);
    argmax_kernel<<<B * SDEC, 256, 0, stream>>>(out + B * SDEC, out);
}

// Round 3
// 10866.253 us; speedup vs baseline: 1.0290x; 1.0290x over previous
//
#include <hip/hip_runtime.h>
#include <hip/hip_bf16.h>
#include <math.h>

// Problem constants
#define B 32
#define SENC 64
#define SDEC 32
#define HDIM 512
#define EDIM 512
#define VDIM 32000
#define G4 2048              // 4*H
#define BH (B*HDIM)          // 16384

#define WS 516               // enc LDS row stride
#define PBS 17               // enc pbuf row stride
#define WCS 1028             // dec cell weight row stride ([Wih|Whh] + pad)
#define PBD 20               // dec partial stride (16 used, aligned, bank-spread)

__device__ __forceinline__ float sigm(float x) { return 1.f / (1.f + expf(-x)); }

__device__ __forceinline__ float allreduce64(float v)
{
    #pragma unroll
    for (int m = 1; m < 64; m <<= 1) v += __shfl_xor(v, m);
    return v;
}

// Lean grid barrier: generation-counting, agent-scope atomics, thread-0 spin.
// cnt/gen zeroed before launch; g starts at 1 and increments per use.
__device__ __forceinline__ void gridbar(int* cnt, int* gen, int nblk, int g)
{
    __syncthreads();
    if (threadIdx.x == 0) {
        __threadfence();
        int a = __hip_atomic_fetch_add(cnt, 1, __ATOMIC_ACQ_REL,
                                       __HIP_MEMORY_SCOPE_AGENT);
        if (a == nblk - 1) {
            __hip_atomic_store(cnt, 0, __ATOMIC_RELAXED, __HIP_MEMORY_SCOPE_AGENT);
            __hip_atomic_store(gen, g, __ATOMIC_RELEASE, __HIP_MEMORY_SCOPE_AGENT);
        } else {
            while (__hip_atomic_load(gen, __ATOMIC_ACQUIRE,
                                     __HIP_MEMORY_SCOPE_AGENT) < g) {
                __builtin_amdgcn_s_sleep(8);
            }
        }
        __threadfence();
    }
    __syncthreads();
}

// ---------------------------------------------------------------------------
__global__ __launch_bounds__(128) void embed_kernel(const int* __restrict__ toks,
                                                    const float* __restrict__ emb,
                                                    float* __restrict__ out)
{
    int t = blockIdx.x;
    int id = toks[t];
    const float4* src = (const float4*)(emb + (size_t)id * EDIM);
    float4* dst = (float4*)(out + (size_t)t * EDIM);
    dst[threadIdx.x] = src[threadIdx.x];
}

// ---------------------------------------------------------------------------
// NT SGEMM: C[m,n] = sum_k A[m*K+k]*B[n*K+k] (+bias0[n]+bias1[n])
// ---------------------------------------------------------------------------
__global__ __launch_bounds__(256) void gemm_nt(const float* __restrict__ A,
                                               const float* __restrict__ Bm,
                                               float* __restrict__ C,
                                               const float* __restrict__ bias0,
                                               const float* __restrict__ bias1,
                                               int M, int N, int K)
{
    __shared__ float As[16][128];
    __shared__ float Bs[16][64];
    int tid = threadIdx.x;
    int tx = tid & 15, ty = tid >> 4;
    int m0 = blockIdx.y * 128, n0 = blockIdx.x * 64;

    float acc[8][4];
    #pragma unroll
    for (int i = 0; i < 8; i++)
        #pragma unroll
        for (int j = 0; j < 4; j++) acc[i][j] = 0.f;

    int la_m = tid >> 1, la_k = (tid & 1) * 8;
    int lb_n = tid & 63, lb_k = (tid >> 6) * 4;
    const float* Aptr = A + (size_t)(m0 + la_m) * K + la_k;
    const float* Bptr = Bm + (size_t)(n0 + lb_n) * K + lb_k;

    for (int k0 = 0; k0 < K; k0 += 16) {
        float4 a1 = *(const float4*)(Aptr + k0);
        float4 a2 = *(const float4*)(Aptr + k0 + 4);
        float4 bv = *(const float4*)(Bptr + k0);
        As[la_k + 0][la_m] = a1.x; As[la_k + 1][la_m] = a1.y;
        As[la_k + 2][la_m] = a1.z; As[la_k + 3][la_m] = a1.w;
        As[la_k + 4][la_m] = a2.x; As[la_k + 5][la_m] = a2.y;
        As[la_k + 6][la_m] = a2.z; As[la_k + 7][la_m] = a2.w;
        Bs[lb_k + 0][lb_n] = bv.x; Bs[lb_k + 1][lb_n] = bv.y;
        Bs[lb_k + 2][lb_n] = bv.z; Bs[lb_k + 3][lb_n] = bv.w;
        __syncthreads();
        #pragma unroll
        for (int kk = 0; kk < 16; kk++) {
            float4 av1 = *(const float4*)&As[kk][ty * 8];
            float4 av2 = *(const float4*)&As[kk][ty * 8 + 4];
            float4 bvv = *(const float4*)&Bs[kk][tx * 4];
            float am[8] = {av1.x, av1.y, av1.z, av1.w, av2.x, av2.y, av2.z, av2.w};
            float bn[4] = {bvv.x, bvv.y, bvv.z, bvv.w};
            #pragma unroll
            for (int i = 0; i < 8; i++)
                #pragma unroll
                for (int j = 0; j < 4; j++)
                    acc[i][j] += am[i] * bn[j];
        }
        __syncthreads();
    }

    float bb[4] = {0.f, 0.f, 0.f, 0.f};
    int nc = n0 + tx * 4;
    if (bias0) {
        #pragma unroll
        for (int j = 0; j < 4; j++) bb[j] += bias0[nc + j];
    }
    if (bias1) {
        #pragma unroll
        for (int j = 0; j < 4; j++) bb[j] += bias1[nc + j];
    }
    #pragma unroll
    for (int i = 0; i < 8; i++) {
        int row = m0 + ty * 8 + i;
        float4 o = make_float4(acc[i][0] + bb[0], acc[i][1] + bb[1],
                               acc[i][2] + bb[2], acc[i][3] + bb[3]);
        *(float4*)(C + (size_t)row * N + nc) = o;
    }
}

// ---------------------------------------------------------------------------
// NN SGEMM: C[m,n] = sum_k A[m*K+k]*B[k*N+n]   (for M = enc_out @ attnW)
// ---------------------------------------------------------------------------
__global__ __launch_bounds__(256) void gemm_nn(const float* __restrict__ A,
                                               const float* __restrict__ Bm,
                                               float* __restrict__ C,
                                               int M, int N, int K)
{
    __shared__ float As[16][128];
    __shared__ float Bs[16][64];
    int tid = threadIdx.x;
    int tx = tid & 15, ty = tid >> 4;
    int m0 = blockIdx.y * 128, n0 = blockIdx.x * 64;

    float acc[8][4];
    #pragma unroll
    for (int i = 0; i < 8; i++)
        #pragma unroll
        for (int j = 0; j < 4; j++) acc[i][j] = 0.f;

    int la_m = tid >> 1, la_k = (tid & 1) * 8;
    int lb_k = tid >> 4, lb_n = (tid & 15) * 4;
    const float* Aptr = A + (size_t)(m0 + la_m) * K + la_k;
    const float* Bptr = Bm + (size_t)lb_k * N + n0 + lb_n;

    for (int k0 = 0; k0 < K; k0 += 16) {
        float4 a1 = *(const float4*)(Aptr + k0);
        float4 a2 = *(const float4*)(Aptr + k0 + 4);
        float4 bv = *(const float4*)(Bptr + (size_t)k0 * N);
        As[la_k + 0][la_m] = a1.x; As[la_k + 1][la_m] = a1.y;
        As[la_k + 2][la_m] = a1.z; As[la_k + 3][la_m] = a1.w;
        As[la_k + 4][la_m] = a2.x; As[la_k + 5][la_m] = a2.y;
        As[la_k + 6][la_m] = a2.z; As[la_k + 7][la_m] = a2.w;
        *(float4*)&Bs[lb_k][lb_n] = bv;
        __syncthreads();
        #pragma unroll
        for (int kk = 0; kk < 16; kk++) {
            float4 av1 = *(const float4*)&As[kk][ty * 8];
            float4 av2 = *(const float4*)&As[kk][ty * 8 + 4];
            float4 bvv = *(const float4*)&Bs[kk][tx * 4];
            float am[8] = {av1.x, av1.y, av1.z, av1.w, av2.x, av2.y, av2.z, av2.w};
            float bn[4] = {bvv.x, bvv.y, bvv.z, bvv.w};
            #pragma unroll
            for (int i = 0; i < 8; i++)
                #pragma unroll
                for (int j = 0; j < 4; j++)
                    acc[i][j] += am[i] * bn[j];
        }
        __syncthreads();
    }
    #pragma unroll
    for (int i = 0; i < 8; i++) {
        int row = m0 + ty * 8 + i;
        float4 o = make_float4(acc[i][0], acc[i][1], acc[i][2], acc[i][3]);
        *(float4*)(C + (size_t)row * N + n0 + tx * 4) = o;
    }
}

// ---------------------------------------------------------------------------
// Persistent encoder layer (round-2 structure, custom barrier).
// ---------------------------------------------------------------------------
__global__ __launch_bounds__(256, 1) void enc_layer(
    const float* __restrict__ xg,
    const float* __restrict__ Whh,
    float* __restrict__ seq_out,
    float* __restrict__ hping,
    float* __restrict__ hT,
    float* __restrict__ cT,
    int* __restrict__ bar)
{
    int* cnt = bar;
    int* gen = bar + 1;
    __shared__ float wsh[16 * WS];
    __shared__ float hsh[16 * WS];
    __shared__ float pbuf[4 * 16 * PBS];

    int tid = threadIdx.x;
    int cid = blockIdx.x >> 1, bg = blockIdx.x & 1;
    int jh0 = cid * 4, b0 = bg * 16;

    for (int idx = tid; idx < 16 * 128; idx += 256) {
        int r = idx >> 7, kq = idx & 127;
        int grow = (r >> 2) * 512 + jh0 + (r & 3);
        *(float4*)(wsh + r * WS + kq * 4) =
            *(const float4*)(Whh + (size_t)grow * 512 + kq * 4);
    }

    int kseg = tid >> 6, rp = (tid >> 3) & 7, bp = tid & 7;
    const float* w0 = wsh + (2 * rp) * WS + kseg * 128;
    const float* w1 = wsh + (2 * rp + 1) * WS + kseg * 128;
    const float* h0 = hsh + (2 * bp) * WS + kseg * 128;
    const float* h1 = hsh + (2 * bp + 1) * WS + kseg * 128;

    int pjl = tid >> 4, pb = tid & 15;
    float c_reg = 0.f;
    int g = 0;

    for (int t = 0; t < SENC; t++) {
        const float* hin = hping + (t & 1) * BH;
        float* hout = hping + ((t & 1) ^ 1) * BH;
        if (t == 0) {
            float4 z = make_float4(0.f, 0.f, 0.f, 0.f);
            for (int idx = tid; idx < 16 * 128; idx += 256)
                *(float4*)(hsh + (idx >> 7) * WS + (idx & 127) * 4) = z;
        } else {
            for (int idx = tid; idx < 16 * 128; idx += 256) {
                int bb = idx >> 7, kq = idx & 127;
                *(float4*)(hsh + bb * WS + kq * 4) =
                    *(const float4*)(hin + (size_t)(b0 + bb) * 512 + kq * 4);
            }
        }
        __syncthreads();

        float s00 = 0.f, s01 = 0.f, s10 = 0.f, s11 = 0.f;
        #pragma unroll 4
        for (int k = 0; k < 128; k += 4) {
            float4 wa = *(const float4*)(w0 + k);
            float4 wb = *(const float4*)(w1 + k);
            float4 xa = *(const float4*)(h0 + k);
            float4 xb = *(const float4*)(h1 + k);
            s00 += wa.x * xa.x + wa.y * xa.y + wa.z * xa.z + wa.w * xa.w;
            s01 += wa.x * xb.x + wa.y * xb.y + wa.z * xb.z + wa.w * xb.w;
            s10 += wb.x * xa.x + wb.y * xa.y + wb.z * xa.z + wb.w * xa.w;
            s11 += wb.x * xb.x + wb.y * xb.y + wb.z * xb.z + wb.w * xb.w;
        }
        pbuf[(kseg * 16 + 2 * rp) * PBS + 2 * bp]         = s00;
        pbuf[(kseg * 16 + 2 * rp) * PBS + 2 * bp + 1]     = s01;
        pbuf[(kseg * 16 + 2 * rp + 1) * PBS + 2 * bp]     = s10;
        pbuf[(kseg * 16 + 2 * rp + 1) * PBS + 2 * bp + 1] = s11;
        __syncthreads();

        if (tid < 64) {
            int bglob = b0 + pb, jh = jh0 + pjl;
            size_t xrow = (size_t)(bglob * SENC + t) * G4;
            float gv[4];
            #pragma unroll
            for (int gi = 0; gi < 4; gi++) {
                int r = gi * 4 + pjl;
                gv[gi] = pbuf[(0 * 16 + r) * PBS + pb] + pbuf[(1 * 16 + r) * PBS + pb]
                       + pbuf[(2 * 16 + r) * PBS + pb] + pbuf[(3 * 16 + r) * PBS + pb]
                       + xg[xrow + gi * 512 + jh];
            }
            float ci = sigm(gv[0]), cf = sigm(gv[1]);
            float cg_ = tanhf(gv[2]), co = sigm(gv[3]);
            c_reg = cf * c_reg + ci * cg_;
            float hn = co * tanhf(c_reg);
            hout[bglob * 512 + jh] = hn;
            seq_out[(size_t)(bglob * SENC + t) * 512 + jh] = hn;
            if (t == SENC - 1) {
                hT[bglob * 512 + jh] = hn;
                cT[bglob * 512 + jh] = c_reg;
            }
        }
        g++;
        gridbar(cnt, gen, 256, g);
    }
}

// ---------------------------------------------------------------------------
// Persistent decoder v2: weights LDS-resident; 4 barriers/step.
// Block cid owns gate-rows gi*512 + cid*2 + j (j=0,1) of both layers and
// comb rows cid*2 + j.
// ---------------------------------------------------------------------------
__global__ __launch_bounds__(256, 1) void dec_seq(
    const int* __restrict__ xs, const int* __restrict__ ys,
    const float* __restrict__ emb,
    const float* __restrict__ combW,
    const float* __restrict__ Wih0, const float* __restrict__ Whh0,
    const float* __restrict__ bih0, const float* __restrict__ bhh0,
    const float* __restrict__ Wih1, const float* __restrict__ Whh1,
    const float* __restrict__ bih1, const float* __restrict__ bhh1,
    const float* __restrict__ enc_out,
    const float* __restrict__ Mbuf,
    const float* __restrict__ c0init, const float* __restrict__ c1init,
    float* __restrict__ hb0,
    float* __restrict__ hb1,
    float* __restrict__ xc_g,
    float* __restrict__ inp_g,
    float* __restrict__ h2buf,
    int* __restrict__ bar)
{
    int* cnt = bar;
    int* gen = bar + 1;
    __shared__ float wc[2][8][WCS];
    __shared__ float wcb[2][WCS];
    __shared__ float pbuf[8 * 32 * PBD];
    __shared__ float msc[648];

    int tid = threadIdx.x;
    int cid = blockIdx.x;

    // one-time weight staging
    for (int idx = tid; idx < 4096; idx += 256) {
        int l = idx >> 11, rem = idx & 2047;
        int rl = rem >> 8, kq = rem & 255;
        int k = kq * 4;
        int grow = (rl >> 1) * 512 + cid * 2 + (rl & 1);
        const float* Wih = l ? Wih1 : Wih0;
        const float* Whh = l ? Whh1 : Whh0;
        const float* src = (k < 512) ? (Wih + (size_t)grow * 512 + k)
                                     : (Whh + (size_t)grow * 512 + (k - 512));
        *(float4*)&wc[l][rl][k] = *(const float4*)src;
    }
    for (int idx = tid; idx < 512; idx += 256) {
        int rg = idx >> 8, kq = idx & 255;
        *(float4*)&wcb[rg][kq * 4] =
            *(const float4*)(combW + (size_t)(cid * 2 + rg) * 1024 + kq * 4);
    }

    int pjl = tid >> 5, pb = tid & 31;
    float c0 = 0.f, c1 = 0.f;
    float bs0[4], bs1[4];
    if (tid < 64) {
        int jh = cid * 2 + pjl;
        c0 = c0init[pb * 512 + jh];
        c1 = c1init[pb * 512 + jh];
        #pragma unroll
        for (int gi = 0; gi < 4; gi++) {
            int grow = gi * 512 + jh;
            bs0[gi] = bih0[grow] + bhh0[grow];
            bs1[gi] = bih1[grow] + bhh1[grow];
        }
    }
    __syncthreads();

    int ks = tid >> 4, bg = (tid >> 1) & 7, rg = tid & 1;

    int p0 = 0, p1 = 0, g = 0;
    for (int t = 0; t < SDEC; t++) {
        // ---- phase A: attention via M (blocks 0..31) ----
        if (cid < 32) {
            int b = cid;
            float* h2s = msc;
            float* pw = msc + 512;
            float* aw = msc + 576;
            const float* h2 = hb1 + p1 * BH + b * 512;
            int yt = ys[b * SDEC + t];
            for (int i = tid; i < 512; i += 256) {
                h2s[i] = h2[i];
                xc_g[b * 1024 + i] = emb[(size_t)yt * EDIM + i];
            }
            __syncthreads();
            int wave = tid >> 6, lane = tid & 63;
            float4 hv1 = *(const float4*)(h2s + lane * 8);
            float4 hv2 = *(const float4*)(h2s + lane * 8 + 4);
            #pragma unroll
            for (int ii = 0; ii < 16; ii++) {
                int s = wave * 16 + ii;
                const float* mr = Mbuf + (size_t)(b * SENC + s) * 512 + lane * 8;
                float4 m1 = *(const float4*)mr;
                float4 m2 = *(const float4*)(mr + 4);
                float pp = m1.x * hv1.x + m1.y * hv1.y + m1.z * hv1.z + m1.w * hv1.w
                         + m2.x * hv2.x + m2.y * hv2.y + m2.z * hv2.z + m2.w * hv2.w;
                pp = allreduce64(pp);
                if (lane == 0)
                    pw[s] = pp - ((xs[b * SENC + s] > 0) ? 0.f : 1e20f);
            }
            __syncthreads();
            if (tid < 64) {
                float v = pw[tid];
                float m = v;
                #pragma unroll
                for (int o = 1; o < 64; o <<= 1) m = fmaxf(m, __shfl_xor(m, o));
                float ex = expf(v - m);
                float sm = ex;
                #pragma unroll
                for (int o = 1; o < 64; o <<= 1) sm += __shfl_xor(sm, o);
                aw[tid] = ex / sm;
            }
            __syncthreads();
            for (int e = tid; e < 512; e += 256) {
                float acc = 0.f;
                #pragma unroll 8
                for (int ss = 0; ss < 64; ss++)
                    acc += aw[ss] * enc_out[(size_t)(b * SENC + ss) * 512 + e];
                xc_g[b * 1024 + 512 + e] = acc;
            }
        }
        g++; gridbar(cnt, gen, 256, g);

        // ---- phase B: comb ----
        {
            int ksc = tid >> 6, bb = (tid >> 1) & 31, rgc = tid & 1;
            const float* xr = xc_g + bb * 1024 + ksc * 256;
            const float* wr = &wcb[rgc][ksc * 256];
            float acc = 0.f;
            #pragma unroll 4
            for (int kk = 0; kk < 256; kk += 4) {
                float4 xv = *(const float4*)(xr + kk);
                float4 wv = *(const float4*)(wr + kk);
                acc += xv.x * wv.x + xv.y * wv.y + xv.z * wv.z + xv.w * wv.w;
            }
            pbuf[(rgc * 32 + bb) * PBD + ksc] = acc;
        }
        __syncthreads();
        if (tid < 64) {
            int rgc = tid >> 5, bb = tid & 31;
            const float* p = &pbuf[(rgc * 32 + bb) * PBD];
            float v = p[0] + p[1] + p[2] + p[3];
            inp_g[bb * 512 + cid * 2 + rgc] = tanhf(v);
        }
        g++; gridbar(cnt, gen, 256, g);

        // ---- phases C/D: LSTM cells ----
        #pragma unroll
        for (int layer = 0; layer < 2; layer++) {
            const float* iv = (layer == 0) ? inp_g : (hb0 + (p0 ^ 1) * BH);
            const float* hp = (layer == 0) ? (hb0 + p0 * BH) : (hb1 + p1 * BH);
            float* hnew = (layer == 0) ? (hb0 + (p0 ^ 1) * BH) : (hb1 + (p1 ^ 1) * BH);

            int kofs = ks * 64;
            const float* ab[4];
            #pragma unroll
            for (int u = 0; u < 4; u++) {
                int b = bg * 4 + u;
                ab[u] = (ks < 8) ? (iv + b * 512 + kofs)
                                 : (hp + b * 512 + (kofs - 512));
            }
            const float* wr[4];
            #pragma unroll
            for (int i = 0; i < 4; i++)
                wr[i] = &wc[layer][rg * 4 + i][kofs];

            float acc[4][4];
            #pragma unroll
            for (int i = 0; i < 4; i++)
                #pragma unroll
                for (int u = 0; u < 4; u++) acc[i][u] = 0.f;

            #pragma unroll 4
            for (int kk = 0; kk < 64; kk += 4) {
                float4 av[4], wv[4];
                #pragma unroll
                for (int u = 0; u < 4; u++) av[u] = *(const float4*)(ab[u] + kk);
                #pragma unroll
                for (int i = 0; i < 4; i++) wv[i] = *(const float4*)(wr[i] + kk);
                #pragma unroll
                for (int i = 0; i < 4; i++)
                    #pragma unroll
                    for (int u = 0; u < 4; u++)
                        acc[i][u] += wv[i].x * av[u].x + wv[i].y * av[u].y
                                   + wv[i].z * av[u].z + wv[i].w * av[u].w;
            }
            #pragma unroll
            for (int i = 0; i < 4; i++)
                #pragma unroll
                for (int u = 0; u < 4; u++)
                    pbuf[((rg * 4 + i) * 32 + bg * 4 + u) * PBD + ks] = acc[i][u];
            __syncthreads();

            if (tid < 64) {
                float gv[4];
                #pragma unroll
                for (int gi = 0; gi < 4; gi++) {
                    int rl = gi * 2 + pjl;
                    const float* p = &pbuf[(rl * 32 + pb) * PBD];
                    float4 q0 = *(const float4*)(p + 0);
                    float4 q1 = *(const float4*)(p + 4);
                    float4 q2 = *(const float4*)(p + 8);
                    float4 q3 = *(const float4*)(p + 12);
                    gv[gi] = q0.x + q0.y + q0.z + q0.w + q1.x + q1.y + q1.z + q1.w
                           + q2.x + q2.y + q2.z + q2.w + q3.x + q3.y + q3.z + q3.w
                           + ((layer == 0) ? bs0[gi] : bs1[gi]);
                }
                float ci = sigm(gv[0]), cf = sigm(gv[1]);
                float cg_ = tanhf(gv[2]), co = sigm(gv[3]);
                float& cref = (layer == 0) ? c0 : c1;
                cref = cf * cref + ci * cg_;
                float hn = co * tanhf(cref);
                int jh = cid * 2 + pjl;
                hnew[pb * 512 + jh] = hn;
                if (layer == 1)
                    h2buf[(size_t)(pb * SDEC + t) * 512 + jh] = hn;
            }
            g++; gridbar(cnt, gen, 256, g);
        }
        p0 ^= 1;
        p1 ^= 1;
    }
}

// ---------------------------------------------------------------------------
__global__ __launch_bounds__(256) void argmax_kernel(const float* __restrict__ scores,
                                                     float* __restrict__ preds)
{
    __shared__ float sv[256];
    __shared__ int si[256];
    int m = blockIdx.x;
    const float* row = scores + (size_t)m * VDIM;
    float best = -3.4e38f;
    int bi = 0x7fffffff;
    for (int v = 1 + (int)threadIdx.x; v < VDIM; v += 256) {
        float val = row[v];
        if (val > best) { best = val; bi = v; }
    }
    sv[threadIdx.x] = best;
    si[threadIdx.x] = bi;
    __syncthreads();
    for (int s = 128; s > 0; s >>= 1) {
        if ((int)threadIdx.x < s) {
            float ov = sv[threadIdx.x + s];
            int oi = si[threadIdx.x + s];
            if (ov > sv[threadIdx.x] ||
                (ov == sv[threadIdx.x] && oi < si[threadIdx.x])) {
                sv[threadIdx.x] = ov;
                si[threadIdx.x] = oi;
            }
        }
        __syncthreads();
    }
    if (threadIdx.x == 0) preds[m] = (float)si[0];
}

// ---------------------------------------------------------------------------
extern "C" void kernel_launch(void* const* d_in, const int* in_sizes, int n_in,
                              void* d_out, int out_size, void* d_ws, size_t ws_size,
                              hipStream_t stream)
{
    const int* xs = (const int*)d_in[0];
    const int* ys = (const int*)d_in[1];
    const float* emb = (const float*)d_in[2];
    const float* W[16];
    for (int i = 0; i < 16; i++) W[i] = (const float*)d_in[3 + i];
    const float* attnW = (const float*)d_in[19];
    const float* combW = (const float*)d_in[20];
    float* out = (float*)d_out;
    float* ws = (float*)d_ws;

    float* xemb  = ws;                    // 1,048,576
    float* xg    = xemb + 1048576;        // 4,194,304
    float* l0out = xg + 4194304;          // 1,048,576
    float* l1out = l0out + 1048576;       // 1,048,576 (enc_out)
    float* ench  = l1out + 1048576;       // 2*BH
    float* hb0   = ench + 2 * BH;         // 2*BH
    float* hb1   = hb0 + 2 * BH;          // 2*BH
    float* c0buf = hb1 + 2 * BH;          // BH
    float* c1buf = c0buf + BH;            // BH
    int*   barbuf = (int*)(c1buf + BH);   // 8 ints
    float* Mbuf  = xg;                    // overlay (xg dead post-encoder)
    float* xc_g  = xg + 1048576;
    float* inp_g = xc_g + B * 1024;
    float* h2buf = xemb;                  // overlay (xemb dead post-L0-gemm)

    hipMemsetAsync(barbuf, 0, 8 * sizeof(int), stream);

    embed_kernel<<<B * SENC, 128, 0, stream>>>(xs, emb, xemb);

    gemm_nt<<<dim3(G4 / 64, (B * SENC) / 128), 256, 0, stream>>>(
        xemb, W[0], xg, W[2], W[3], B * SENC, G4, 512);
    {
        const float* a_xg = xg; const float* a_whh = W[1];
        float* a_seq = l0out; float* a_hp = ench;
        float* a_hT = hb0; float* a_cT = c0buf;
        int* a_bar = barbuf;
        void* args[] = {(void*)&a_xg, (void*)&a_whh, (void*)&a_seq,
                        (void*)&a_hp, (void*)&a_hT, (void*)&a_cT, (void*)&a_bar};
        hipLaunchCooperativeKernel((void*)enc_layer, dim3(256), dim3(256),
                                   args, 0, stream);
    }
    gemm_nt<<<dim3(G4 / 64, (B * SENC) / 128), 256, 0, stream>>>(
        l0out, W[4], xg, W[6], W[7], B * SENC, G4, 512);
    {
        const float* a_xg = xg; const float* a_whh = W[5];
        float* a_seq = l1out; float* a_hp = ench;
        float* a_hT = hb1; float* a_cT = c1buf;
        int* a_bar = barbuf + 2;
        void* args[] = {(void*)&a_xg, (void*)&a_whh, (void*)&a_seq,
                        (void*)&a_hp, (void*)&a_hT, (void*)&a_cT, (void*)&a_bar};
        hipLaunchCooperativeKernel((void*)enc_layer, dim3(256), dim3(256),
                                   args, 0, stream);
    }

    gemm_nn<<<dim3(512 / 64, (B * SENC) / 128), 256, 0, stream>>>(
        l1out, attnW, Mbuf, B * SENC, 512, 512);

    {
        const int* a_xs = xs; const int* a_ys = ys;
        const float* a_emb = emb; const float* a_comb = combW;
        const float* a_wih0 = W[8];  const float* a_whh0 = W[9];
        const float* a_bih0 = W[10]; const float* a_bhh0 = W[11];
        const float* a_wih1 = W[12]; const float* a_whh1 = W[13];
        const float* a_bih1 = W[14]; const float* a_bhh1 = W[15];
        const float* a_enc = l1out; const float* a_M = Mbuf;
        const float* a_c0 = c0buf; const float* a_c1 = c1buf;
        float* a_hb0 = hb0; float* a_hb1 = hb1;
        float* a_xc = xc_g; float* a_inp = inp_g; float* a_h2 = h2buf;
        int* a_bar = barbuf + 4;
        void* args[] = {(void*)&a_xs, (void*)&a_ys, (void*)&a_emb, (void*)&a_comb,
                        (void*)&a_wih0, (void*)&a_whh0, (void*)&a_bih0, (void*)&a_bhh0,
                        (void*)&a_wih1, (void*)&a_whh1, (void*)&a_bih1, (void*)&a_bhh1,
                        (void*)&a_enc, (void*)&a_M, (void*)&a_c0, (void*)&a_c1,
                        (void*)&a_hb0, (void*)&a_hb1,
                        (void*)&a_xc, (void*)&a_inp, (void*)&a_h2, (void*)&a_bar};
        hipLaunchCooperativeKernel((void*)dec_seq, dim3(256), dim3(256),
                                   args, 0, stream);
    }

    gemm_nt<<<dim3(VDIM / 64, (B * SDEC) / 128), 256, 0, stream>>>(
        h2buf, emb, out + B * SDEC, nullptr, nullptr, B * SDEC, VDIM, 512);
    argmax_kernel<<<B * SDEC, 256, 0, stream>>>(out + B * SDEC, out);
}